// Round 18
// baseline (184.177 us; speedup 1.0000x reference)
//
#include <hip/hip_runtime.h>

// Capsule EM routing. B=32, H=W=8, I=32 -> N=2048, O=64, P=16, routings=3.
//
// R18: 2-way ILP against the serial chain. Seven single-resource theories
// dead (occupancy, ramp, DS-pose, L1-scatter, w-volume, SMEM latency,
// VGPR cap); body issue is ~4.7us/pass yet body elapsed ~27us, VALUBusy
// ~35%. Last mechanism: each iteration is ONE serial chain (16 dep FMA ->
// exp -> 6 dependent ds_bpermute shuffle-adds @ ~120cy DS latency -> div)
// ~= 1.1k cyc vs 350 cyc issue. Fix: interleave sites sl and sl+4 in one
// body (4 iters x 2 rows; same w serves both) -> two independent chains
// per wave overlap. +16 VGPR (vB) fits the (1024,1) 128-cap (R17).
// A applied to accumulators fully before B -> same summation order.
// Everything else bit-identical to R17/R15.
// Kept lessons: no unroll pragmas (R4), no LDS fp32 atomics (R3), no grid
// sync (R6/R10), one coop atomic flush (R13), stable (v-m)^2 math (R11),
// max-hoisted softmax + SMEM pose/act (R15).

#define NB 32
#define NN 2048
#define NO 64
#define NP 16
#define EPSF 1e-7f

#define SITES_PB 8
#define IS_PB 16

#define ACC_SLOTS 33
#define ACC_PER_B (ACC_SLOTS * NO)    // 2112 floats
#define ACC_TOTAL (NB * ACC_PER_B)    // 67584 floats

template <bool FIRST>
__global__ __launch_bounds__(1024, 1) void accum_kernel(
    const float* __restrict__ pose,        // [B][N][16]
    const float* __restrict__ act,         // [B][N]
    const float* __restrict__ wmat,        // [32][64][16]
    const float* __restrict__ beta_v,      // [64]
    const float* __restrict__ beta_a,      // [64]
    const float* __restrict__ accum_prev,  // [B][33][64] summed, or null
    float* __restrict__ accum_out,         // [B][33][64] pre-zeroed
    float inv_temp)                        // temperature of the PREV iter
{
    __shared__ float stats_s[ACC_PER_B];      // 8448 B (slot32 = zzb - K)
    __shared__ float buf[4][ACC_PER_B];       // 33.8 KB reduce buffers

    const int b = blockIdx.y;
    const int sg = blockIdx.x >> 1;           // site-group 0..7 (8 sites)
    const int ig = blockIdx.x & 1;            // i-group 0..1 (16 i)
    const int s0 = sg * SITES_PB;
    const int tid = threadIdx.x;
    const int w = tid >> 6;                   // wave 0..15 -> i = ig*16+w
    const int o = tid & 63;                   // lane = output capsule
    const int i = ig * 16 + w;
    const int grp = w >> 2, wvin = w & 3;     // reduce grouping

    // ---- wave-persistent w row: loaded once ----
    const float4* wp = (const float4*)(wmat + ((size_t)i * 64 + o) * 16);
    float4 w0 = wp[0], w1 = wp[1], w2 = wp[2], w3 = wp[3];

    // ---- stats of previous pass: WAVE 0 ONLY -> stats_s ----
    if (!FIRST && tid < 64) {
        const float* ap = accum_prev + (size_t)b * ACC_PER_B;
        float rps = ap[32 * 64 + o];
        float rinv = 1.0f / rps;
        float logsum = 0.f;
        float mm[16], vv[16];
        #pragma unroll
        for (int p = 0; p < 16; p++) {
            float mv = ap[p * 64 + o] * rinv;
            float va = fmaxf(ap[(16 + p) * 64 + o] * rinv - mv * mv, 0.f);
            mm[p] = mv;
            vv[p] = va;
            logsum += __logf(sqrtf(va) + EPSF);
        }
        float cost = rps * (16.0f * beta_v[o] + logsum);
        float cm = cost;
        #pragma unroll
        for (int s = 32; s > 0; s >>= 1) cm += __shfl_xor(cm, s, 64);
        cm *= (1.0f / 64.0f);
        float dd = cost - cm;
        float cs = dd * dd;
        #pragma unroll
        for (int s = 32; s > 0; s >>= 1) cs += __shfl_xor(cs, s, 64);
        cs = sqrtf(cs * (1.0f / 64.0f));
        float x = inv_temp * (beta_a[o] + (cm - cost) / (cs + EPSF));
        float oa = 1.0f / (1.0f + __expf(-x));
        float zzb = __logf(oa + EPSF) - logsum;
        float K = zzb;
        #pragma unroll
        for (int s = 32; s > 0; s >>= 1) K = fmaxf(K, __shfl_xor(K, s, 64));
        #pragma unroll
        for (int p = 0; p < 16; p++) stats_s[p * 64 + o] = mm[p];
        #pragma unroll
        for (int p = 0; p < 16; p++) stats_s[(16 + p) * 64 + o] = 0.5f / vv[p];
        stats_s[32 * 64 + o] = zzb - K;
    }
    __syncthreads();   // stats visible

    float m[16], i2v[16], zzbK = 0.f;
    if (!FIRST) {
        #pragma unroll
        for (int p = 0; p < 16; p++) m[p] = stats_s[p * 64 + o];
        #pragma unroll
        for (int p = 0; p < 16; p++) i2v[p] = stats_s[(16 + p) * 64 + o];
        zzbK = stats_s[32 * 64 + o];
    }

    float accR = 0.f, acc1[16], acc2[16];
    #pragma unroll
    for (int p = 0; p < 16; p++) { acc1[p] = 0.f; acc2[p] = 0.f; }

    const int base_n = __builtin_amdgcn_readfirstlane(s0 * 32 + ig * 16 + w);
    const float* pose_b = pose + (size_t)b * NN * 16;
    const float* act_b  = act + (size_t)b * NN;

    // ---- 2-way interleaved inner loop: rows slA = sl, slB = sl+4 ----
    for (int sl = 0; sl < 4; sl++) {
        const int siteA = s0 + sl, siteB = s0 + sl + 4;
        const float c0A = ((siteA >> 3) + 0.5f) * 0.125f;
        const float c1A = ((siteA & 7) + 0.5f) * 0.125f;
        const float c0B = ((siteB >> 3) + 0.5f) * 0.125f;
        const float c1B = ((siteB & 7) + 0.5f) * 0.125f;
        const int nA = base_n + sl * 32;
        const int nB = base_n + (sl + 4) * 32;
        const float4* prA = (const float4*)(pose_b + (size_t)nA * 16);
        const float4* prB = (const float4*)(pose_b + (size_t)nB * 16);
        const float avA = act_b[nA];
        const float avB = act_b[nB];

        float vA[16], vB[16];
        #pragma unroll
        for (int a = 0; a < 4; a++) {
            float4 pa = prA[a];
            vA[a * 4 + 0] = pa.x * w0.x + pa.y * w1.x + pa.z * w2.x + pa.w * w3.x;
            vA[a * 4 + 1] = pa.x * w0.y + pa.y * w1.y + pa.z * w2.y + pa.w * w3.y;
            vA[a * 4 + 2] = pa.x * w0.z + pa.y * w1.z + pa.z * w2.z + pa.w * w3.z;
            vA[a * 4 + 3] = pa.x * w0.w + pa.y * w1.w + pa.z * w2.w + pa.w * w3.w;
        }
        #pragma unroll
        for (int a = 0; a < 4; a++) {
            float4 pa = prB[a];
            vB[a * 4 + 0] = pa.x * w0.x + pa.y * w1.x + pa.z * w2.x + pa.w * w3.x;
            vB[a * 4 + 1] = pa.x * w0.y + pa.y * w1.y + pa.z * w2.y + pa.w * w3.y;
            vB[a * 4 + 2] = pa.x * w0.z + pa.y * w1.z + pa.z * w2.z + pa.w * w3.z;
            vB[a * 4 + 3] = pa.x * w0.w + pa.y * w1.w + pa.z * w2.w + pa.w * w3.w;
        }
        vA[0] += c0A; vA[1] += c1A;
        vB[0] += c0B; vB[1] += c1B;

        float rrA, rrB;
        if (FIRST) {
            rrA = 1.0f / 64.0f;
            rrB = 1.0f / 64.0f;
        } else {
            float dA = zzbK, dB = zzbK;
            #pragma unroll
            for (int p = 0; p < 16; p++) {
                float tA = vA[p] - m[p];
                float tB = vB[p] - m[p];
                dA -= tA * tA * i2v[p];
                dB -= tB * tB * i2v[p];
            }
            float eA = __expf(dA);
            float eB = __expf(dB);
            float sumA = eA, sumB = eB;
            #pragma unroll
            for (int s = 32; s > 0; s >>= 1) {
                sumA += __shfl_xor(sumA, s, 64);
                sumB += __shfl_xor(sumB, s, 64);
            }
            rrA = eA / fmaxf(sumA, 1e-30f);
            rrB = eB / fmaxf(sumB, 1e-30f);
        }
        // apply A fully, then B (matches sequential summation order)
        float rpA = rrA * avA;
        accR += rpA;
        #pragma unroll
        for (int p = 0; p < 16; p++) {
            acc1[p] += rpA * vA[p];
            acc2[p] += rpA * vA[p] * vA[p];
        }
        float rpB = rrB * avB;
        accR += rpB;
        #pragma unroll
        for (int p = 0; p < 16; p++) {
            acc1[p] += rpB * vB[p];
            acc2[p] += rpB * vB[p] * vB[p];
        }
    }

    // ---- R5-proven reduce: barrier-sequenced in-place adds per group ----
    if (wvin == 3) {
        float* r = buf[grp];
        r[32 * 64 + o] = accR;
        #pragma unroll
        for (int p = 0; p < 16; p++) r[p * 64 + o] = acc1[p];
        #pragma unroll
        for (int p = 0; p < 16; p++) r[(16 + p) * 64 + o] = acc2[p];
    }
    __syncthreads();
    if (wvin == 2) {
        float* r = buf[grp];
        r[32 * 64 + o] += accR;
        #pragma unroll
        for (int p = 0; p < 16; p++) r[p * 64 + o] += acc1[p];
        #pragma unroll
        for (int p = 0; p < 16; p++) r[(16 + p) * 64 + o] += acc2[p];
    }
    __syncthreads();
    if (wvin == 1) {
        float* r = buf[grp];
        r[32 * 64 + o] += accR;
        #pragma unroll
        for (int p = 0; p < 16; p++) r[p * 64 + o] += acc1[p];
        #pragma unroll
        for (int p = 0; p < 16; p++) r[(16 + p) * 64 + o] += acc2[p];
    }
    __syncthreads();
    if (wvin == 0) {
        float* r = buf[grp];
        r[32 * 64 + o] += accR;
        #pragma unroll
        for (int p = 0; p < 16; p++) r[p * 64 + o] += acc1[p];
        #pragma unroll
        for (int p = 0; p < 16; p++) r[(16 + p) * 64 + o] += acc2[p];
    }
    __syncthreads();

    // ---- ONE cooperative flush: ~2 coalesced atomics per thread ----
    float* ac = accum_out + (size_t)b * ACC_PER_B;
    for (int j = tid; j < ACC_PER_B; j += 1024)
        atomicAdd(ac + j, buf[0][j] + buf[1][j] + buf[2][j] + buf[3][j]);
}

__global__ __launch_bounds__(64) void stats_final(
    const float* __restrict__ accum,   // [B][33][64] summed
    const float* __restrict__ beta_v,  // [64]
    const float* __restrict__ beta_a,  // [64]
    float* __restrict__ out,
    float inv_temp)
{
    const int b = blockIdx.x;
    const int o = threadIdx.x;  // 64 threads = 1 wave
    const float* ac = accum + (size_t)b * ACC_PER_B;

    float rps = ac[32 * 64 + o];
    float rinv = 1.0f / rps;
    float m[16];
    float logsum = 0.f;
    #pragma unroll
    for (int p = 0; p < 16; p++) {
        float mm = ac[p * 64 + o] * rinv;
        float vv = fmaxf(ac[(16 + p) * 64 + o] * rinv - mm * mm, 0.f);
        m[p] = mm;
        logsum += __logf(sqrtf(vv) + EPSF);
    }
    float cost = rps * (16.0f * beta_v[o] + logsum);

    float cm = cost;
    #pragma unroll
    for (int s = 32; s > 0; s >>= 1) cm += __shfl_xor(cm, s, 64);
    cm *= (1.0f / 64.0f);
    float dd = cost - cm;
    float cs = dd * dd;
    #pragma unroll
    for (int s = 32; s > 0; s >>= 1) cs += __shfl_xor(cs, s, 64);
    cs = sqrtf(cs * (1.0f / 64.0f));

    float x = inv_temp * (beta_a[o] + (cm - cost) / (cs + EPSF));
    float oa = 1.0f / (1.0f + __expf(-x));

    float* op = out + ((size_t)b * 64 + o) * 16;
    #pragma unroll
    for (int p = 0; p < 16; p++) op[p] = m[p];
    out[(size_t)NB * NO * NP + (size_t)b * 64 + o] = oa;
}

extern "C" void kernel_launch(void* const* d_in, const int* in_sizes, int n_in,
                              void* d_out, int out_size, void* d_ws, size_t ws_size,
                              hipStream_t stream) {
    const float* pose   = (const float*)d_in[0];  // (32,8,8,32,4,4)
    const float* act    = (const float*)d_in[1];  // (32,8,8,32)
    const float* wmat   = (const float*)d_in[2];  // (32,64,4,4)
    const float* beta_v = (const float*)d_in[3];  // (1,64)
    const float* beta_a = (const float*)d_in[4];  // (1,64)
    float* out = (float*)d_out;
    float* ws = (float*)d_ws;

    float* a0 = ws;
    float* a1 = ws + (size_t)ACC_TOTAL;
    float* a2 = ws + 2 * (size_t)ACC_TOTAL;

    // zero the three atomic accumulators (ws is poisoned before every call)
    hipMemsetAsync(ws, 0, 3 * (size_t)ACC_TOTAL * sizeof(float), stream);

    dim3 grid(16, NB);   // 512 WGs x 1024 thd
    accum_kernel<true ><<<grid, 1024, 0, stream>>>(pose, act, wmat, beta_v, beta_a,
                                                   nullptr, a0, 0.0f);
    accum_kernel<false><<<grid, 1024, 0, stream>>>(pose, act, wmat, beta_v, beta_a,
                                                   a0, a1, 1.0f);
    accum_kernel<false><<<grid, 1024, 0, stream>>>(pose, act, wmat, beta_v, beta_a,
                                                   a1, a2, 2.0f);
    stats_final<<<NB, 64, 0, stream>>>(a2, beta_v, beta_a, out, 3.0f);
}

// Round 19
// 180.022 us; speedup vs baseline: 1.0231x; 1.0231x over previous
//
#include <hip/hip_runtime.h>

// Capsule EM routing. B=32, H=W=8, I=32 -> N=2048, O=64, P=16, routings=3.
//
// R19: get the 128 VGPRs via the allocator's own heuristic. R18's spill
// (FETCH 16MB / WRITE 53MB at VGPR=64) proved (a) the working set is jammed
// against 64 -- R15's m[]/i2v[] are LDS-reread in-loop (~34 ds_read/iter),
// and (b) launch_bounds(1024,1) does NOT raise the cap (R17 was VOID, not
// null). The allocator budgets registers from its LDS-derived occupancy
// estimate: 42.5KB -> 2 blocks/CU -> 8 waves/SIMD -> 64 VGPR. So pad LDS
// past 80KB -> 1 block/CU -> 4 waves/SIMD -> 128-VGPR budget. Kernel body
// = R18's 2-way ILP (tests register-residency AND chain overlap; ~122 live
// floats fit 128). Occupancy 32->16 waves/CU (prior: occupancy moved accum
// <10%). Validity gate: VGPR 96-128 and FETCH/WRITE back to ~3.7/4.2MB.
// Kept lessons: no unroll pragmas (R4), no LDS fp32 atomics (R3), no grid
// sync (R6/R10), one coop atomic flush (R13), stable (v-m)^2 math (R11),
// max-hoisted softmax + SMEM pose/act (R15).

#define NB 32
#define NN 2048
#define NO 64
#define NP 16
#define EPSF 1e-7f

#define SITES_PB 8
#define IS_PB 16

#define ACC_SLOTS 33
#define ACC_PER_B (ACC_SLOTS * NO)        // 2112 floats
#define ACC_TOTAL (NB * ACC_PER_B)        // 67584 floats
// buf stride padded so total LDS = 8448 + 4*4612*4 = 82240 B > 81920 B
// (half of 160KB) -> only 1 block/CU fits -> allocator budgets 128 VGPRs.
#define BUF_STRIDE (ACC_PER_B + 2500)     // 4612 floats per buffer

template <bool FIRST>
__global__ __launch_bounds__(1024, 1) void accum_kernel(
    const float* __restrict__ pose,        // [B][N][16]
    const float* __restrict__ act,         // [B][N]
    const float* __restrict__ wmat,        // [32][64][16]
    const float* __restrict__ beta_v,      // [64]
    const float* __restrict__ beta_a,      // [64]
    const float* __restrict__ accum_prev,  // [B][33][64] summed, or null
    float* __restrict__ accum_out,         // [B][33][64] pre-zeroed
    float inv_temp)                        // temperature of the PREV iter
{
    __shared__ float stats_s[ACC_PER_B];      // 8448 B (slot32 = zzb - K)
    __shared__ float buf[4][BUF_STRIDE];      // 73.8 KB (stride-padded)

    const int b = blockIdx.y;
    const int sg = blockIdx.x >> 1;           // site-group 0..7 (8 sites)
    const int ig = blockIdx.x & 1;            // i-group 0..1 (16 i)
    const int s0 = sg * SITES_PB;
    const int tid = threadIdx.x;
    const int w = tid >> 6;                   // wave 0..15 -> i = ig*16+w
    const int o = tid & 63;                   // lane = output capsule
    const int i = ig * 16 + w;
    const int grp = w >> 2, wvin = w & 3;     // reduce grouping

    // ---- wave-persistent w row: loaded once ----
    const float4* wp = (const float4*)(wmat + ((size_t)i * 64 + o) * 16);
    float4 w0 = wp[0], w1 = wp[1], w2 = wp[2], w3 = wp[3];

    // ---- stats of previous pass: WAVE 0 ONLY -> stats_s ----
    if (!FIRST && tid < 64) {
        const float* ap = accum_prev + (size_t)b * ACC_PER_B;
        float rps = ap[32 * 64 + o];
        float rinv = 1.0f / rps;
        float logsum = 0.f;
        float mm[16], vv[16];
        #pragma unroll
        for (int p = 0; p < 16; p++) {
            float mv = ap[p * 64 + o] * rinv;
            float va = fmaxf(ap[(16 + p) * 64 + o] * rinv - mv * mv, 0.f);
            mm[p] = mv;
            vv[p] = va;
            logsum += __logf(sqrtf(va) + EPSF);
        }
        float cost = rps * (16.0f * beta_v[o] + logsum);
        float cm = cost;
        #pragma unroll
        for (int s = 32; s > 0; s >>= 1) cm += __shfl_xor(cm, s, 64);
        cm *= (1.0f / 64.0f);
        float dd = cost - cm;
        float cs = dd * dd;
        #pragma unroll
        for (int s = 32; s > 0; s >>= 1) cs += __shfl_xor(cs, s, 64);
        cs = sqrtf(cs * (1.0f / 64.0f));
        float x = inv_temp * (beta_a[o] + (cm - cost) / (cs + EPSF));
        float oa = 1.0f / (1.0f + __expf(-x));
        float zzb = __logf(oa + EPSF) - logsum;
        float K = zzb;
        #pragma unroll
        for (int s = 32; s > 0; s >>= 1) K = fmaxf(K, __shfl_xor(K, s, 64));
        #pragma unroll
        for (int p = 0; p < 16; p++) stats_s[p * 64 + o] = mm[p];
        #pragma unroll
        for (int p = 0; p < 16; p++) stats_s[(16 + p) * 64 + o] = 0.5f / vv[p];
        stats_s[32 * 64 + o] = zzb - K;
    }
    __syncthreads();   // stats visible

    float m[16], i2v[16], zzbK = 0.f;
    if (!FIRST) {
        #pragma unroll
        for (int p = 0; p < 16; p++) m[p] = stats_s[p * 64 + o];
        #pragma unroll
        for (int p = 0; p < 16; p++) i2v[p] = stats_s[(16 + p) * 64 + o];
        zzbK = stats_s[32 * 64 + o];
    }

    float accR = 0.f, acc1[16], acc2[16];
    #pragma unroll
    for (int p = 0; p < 16; p++) { acc1[p] = 0.f; acc2[p] = 0.f; }

    const int base_n = __builtin_amdgcn_readfirstlane(s0 * 32 + ig * 16 + w);
    const float* pose_b = pose + (size_t)b * NN * 16;
    const float* act_b  = act + (size_t)b * NN;

    // ---- 2-way interleaved inner loop: rows slA = sl, slB = sl+4 ----
    for (int sl = 0; sl < 4; sl++) {
        const int siteA = s0 + sl, siteB = s0 + sl + 4;
        const float c0A = ((siteA >> 3) + 0.5f) * 0.125f;
        const float c1A = ((siteA & 7) + 0.5f) * 0.125f;
        const float c0B = ((siteB >> 3) + 0.5f) * 0.125f;
        const float c1B = ((siteB & 7) + 0.5f) * 0.125f;
        const int nA = base_n + sl * 32;
        const int nB = base_n + (sl + 4) * 32;
        const float4* prA = (const float4*)(pose_b + (size_t)nA * 16);
        const float4* prB = (const float4*)(pose_b + (size_t)nB * 16);
        const float avA = act_b[nA];
        const float avB = act_b[nB];

        float vA[16], vB[16];
        #pragma unroll
        for (int a = 0; a < 4; a++) {
            float4 pa = prA[a];
            vA[a * 4 + 0] = pa.x * w0.x + pa.y * w1.x + pa.z * w2.x + pa.w * w3.x;
            vA[a * 4 + 1] = pa.x * w0.y + pa.y * w1.y + pa.z * w2.y + pa.w * w3.y;
            vA[a * 4 + 2] = pa.x * w0.z + pa.y * w1.z + pa.z * w2.z + pa.w * w3.z;
            vA[a * 4 + 3] = pa.x * w0.w + pa.y * w1.w + pa.z * w2.w + pa.w * w3.w;
        }
        #pragma unroll
        for (int a = 0; a < 4; a++) {
            float4 pa = prB[a];
            vB[a * 4 + 0] = pa.x * w0.x + pa.y * w1.x + pa.z * w2.x + pa.w * w3.x;
            vB[a * 4 + 1] = pa.x * w0.y + pa.y * w1.y + pa.z * w2.y + pa.w * w3.y;
            vB[a * 4 + 2] = pa.x * w0.z + pa.y * w1.z + pa.z * w2.z + pa.w * w3.z;
            vB[a * 4 + 3] = pa.x * w0.w + pa.y * w1.w + pa.z * w2.w + pa.w * w3.w;
        }
        vA[0] += c0A; vA[1] += c1A;
        vB[0] += c0B; vB[1] += c1B;

        float rrA, rrB;
        if (FIRST) {
            rrA = 1.0f / 64.0f;
            rrB = 1.0f / 64.0f;
        } else {
            float dA = zzbK, dB = zzbK;
            #pragma unroll
            for (int p = 0; p < 16; p++) {
                float tA = vA[p] - m[p];
                float tB = vB[p] - m[p];
                dA -= tA * tA * i2v[p];
                dB -= tB * tB * i2v[p];
            }
            float eA = __expf(dA);
            float eB = __expf(dB);
            float sumA = eA, sumB = eB;
            #pragma unroll
            for (int s = 32; s > 0; s >>= 1) {
                sumA += __shfl_xor(sumA, s, 64);
                sumB += __shfl_xor(sumB, s, 64);
            }
            rrA = eA / fmaxf(sumA, 1e-30f);
            rrB = eB / fmaxf(sumB, 1e-30f);
        }
        // apply A fully, then B (matches sequential summation order)
        float rpA = rrA * avA;
        accR += rpA;
        #pragma unroll
        for (int p = 0; p < 16; p++) {
            acc1[p] += rpA * vA[p];
            acc2[p] += rpA * vA[p] * vA[p];
        }
        float rpB = rrB * avB;
        accR += rpB;
        #pragma unroll
        for (int p = 0; p < 16; p++) {
            acc1[p] += rpB * vB[p];
            acc2[p] += rpB * vB[p] * vB[p];
        }
    }

    // ---- R5-proven reduce: barrier-sequenced in-place adds per group ----
    if (wvin == 3) {
        float* r = buf[grp];
        r[32 * 64 + o] = accR;
        #pragma unroll
        for (int p = 0; p < 16; p++) r[p * 64 + o] = acc1[p];
        #pragma unroll
        for (int p = 0; p < 16; p++) r[(16 + p) * 64 + o] = acc2[p];
    }
    __syncthreads();
    if (wvin == 2) {
        float* r = buf[grp];
        r[32 * 64 + o] += accR;
        #pragma unroll
        for (int p = 0; p < 16; p++) r[p * 64 + o] += acc1[p];
        #pragma unroll
        for (int p = 0; p < 16; p++) r[(16 + p) * 64 + o] += acc2[p];
    }
    __syncthreads();
    if (wvin == 1) {
        float* r = buf[grp];
        r[32 * 64 + o] += accR;
        #pragma unroll
        for (int p = 0; p < 16; p++) r[p * 64 + o] += acc1[p];
        #pragma unroll
        for (int p = 0; p < 16; p++) r[(16 + p) * 64 + o] += acc2[p];
    }
    __syncthreads();
    if (wvin == 0) {
        float* r = buf[grp];
        r[32 * 64 + o] += accR;
        #pragma unroll
        for (int p = 0; p < 16; p++) r[p * 64 + o] += acc1[p];
        #pragma unroll
        for (int p = 0; p < 16; p++) r[(16 + p) * 64 + o] += acc2[p];
    }
    __syncthreads();

    // ---- ONE cooperative flush: ~2 coalesced atomics per thread ----
    float* ac = accum_out + (size_t)b * ACC_PER_B;
    for (int j = tid; j < ACC_PER_B; j += 1024)
        atomicAdd(ac + j, buf[0][j] + buf[1][j] + buf[2][j] + buf[3][j]);
}

__global__ __launch_bounds__(64) void stats_final(
    const float* __restrict__ accum,   // [B][33][64] summed
    const float* __restrict__ beta_v,  // [64]
    const float* __restrict__ beta_a,  // [64]
    float* __restrict__ out,
    float inv_temp)
{
    const int b = blockIdx.x;
    const int o = threadIdx.x;  // 64 threads = 1 wave
    const float* ac = accum + (size_t)b * ACC_PER_B;

    float rps = ac[32 * 64 + o];
    float rinv = 1.0f / rps;
    float m[16];
    float logsum = 0.f;
    #pragma unroll
    for (int p = 0; p < 16; p++) {
        float mm = ac[p * 64 + o] * rinv;
        float vv = fmaxf(ac[(16 + p) * 64 + o] * rinv - mm * mm, 0.f);
        m[p] = mm;
        logsum += __logf(sqrtf(vv) + EPSF);
    }
    float cost = rps * (16.0f * beta_v[o] + logsum);

    float cm = cost;
    #pragma unroll
    for (int s = 32; s > 0; s >>= 1) cm += __shfl_xor(cm, s, 64);
    cm *= (1.0f / 64.0f);
    float dd = cost - cm;
    float cs = dd * dd;
    #pragma unroll
    for (int s = 32; s > 0; s >>= 1) cs += __shfl_xor(cs, s, 64);
    cs = sqrtf(cs * (1.0f / 64.0f));

    float x = inv_temp * (beta_a[o] + (cm - cost) / (cs + EPSF));
    float oa = 1.0f / (1.0f + __expf(-x));

    float* op = out + ((size_t)b * 64 + o) * 16;
    #pragma unroll
    for (int p = 0; p < 16; p++) op[p] = m[p];
    out[(size_t)NB * NO * NP + (size_t)b * 64 + o] = oa;
}

extern "C" void kernel_launch(void* const* d_in, const int* in_sizes, int n_in,
                              void* d_out, int out_size, void* d_ws, size_t ws_size,
                              hipStream_t stream) {
    const float* pose   = (const float*)d_in[0];  // (32,8,8,32,4,4)
    const float* act    = (const float*)d_in[1];  // (32,8,8,32)
    const float* wmat   = (const float*)d_in[2];  // (32,64,4,4)
    const float* beta_v = (const float*)d_in[3];  // (1,64)
    const float* beta_a = (const float*)d_in[4];  // (1,64)
    float* out = (float*)d_out;
    float* ws = (float*)d_ws;

    float* a0 = ws;
    float* a1 = ws + (size_t)ACC_TOTAL;
    float* a2 = ws + 2 * (size_t)ACC_TOTAL;

    // zero the three atomic accumulators (ws is poisoned before every call)
    hipMemsetAsync(ws, 0, 3 * (size_t)ACC_TOTAL * sizeof(float), stream);

    dim3 grid(16, NB);   // 512 WGs x 1024 thd
    accum_kernel<true ><<<grid, 1024, 0, stream>>>(pose, act, wmat, beta_v, beta_a,
                                                   nullptr, a0, 0.0f);
    accum_kernel<false><<<grid, 1024, 0, stream>>>(pose, act, wmat, beta_v, beta_a,
                                                   a0, a1, 1.0f);
    accum_kernel<false><<<grid, 1024, 0, stream>>>(pose, act, wmat, beta_v, beta_a,
                                                   a1, a2, 2.0f);
    stats_final<<<NB, 64, 0, stream>>>(a2, beta_v, beta_a, out, 3.0f);
}

// Round 20
// 139.790 us; speedup vs baseline: 1.3175x; 1.2878x over previous
//
#include <hip/hip_runtime.h>

// Capsule EM routing. B=32, H=W=8, I=32 -> N=2048, O=64, P=16, routings=3.
//
// R20: registers AND few WGs. Compiler facts established: 1024-thd kernels
// are pinned at 64 VGPR (R17/R18/R19: launch_bounds + LDS-padding both
// failed the gate; +32 floats spilled to scratch) while 256-thd blocks can
// exceed 64 (R12: VGPR=68). Constraints: grid ~512 WGs (ramp(2048)~29us),
// block <=256 thd (VGPR unlock), working set ~100 floats register-resident
// (kill the in-loop m/i2v LDS rereads proven by R18's jam). Shape: 512 WGs
// x 256 thd; wave = one i x 32 sites (block = 4 i x 32 sites; 16 blocks/
// batch). launch_bounds(256,2): CUDA semantics (2 blocks/CU -> 2 waves/
// SIMD) and waves/EU semantics (2/EU) BOTH give cap >=256 -- first knob
// where the two interpretations agree. Body = R15-proven (SMEM pose/act,
// max-hoisted softmax, stable (v-m)^2); reduce = R1-proven 4-wave tree +
// wave0 atomic flush. Validity gate: VGPR >= 96, FETCH/WRITE ~3.7/4.2MB.
// Kept lessons: no unroll pragmas (R4), no LDS fp32 atomics (R3), no grid
// sync (R6/R10), no per-wave direct atomics (R13).

#define NB 32
#define NN 2048
#define NO 64
#define NP 16
#define EPSF 1e-7f

#define ACC_SLOTS 33
#define ACC_PER_B (ACC_SLOTS * NO)    // 2112 floats
#define ACC_TOTAL (NB * ACC_PER_B)    // 67584 floats

template <bool FIRST>
__global__ __launch_bounds__(256, 2) void accum_kernel(
    const float* __restrict__ pose,        // [B][N][16]
    const float* __restrict__ act,         // [B][N]
    const float* __restrict__ wmat,        // [32][64][16]
    const float* __restrict__ beta_v,      // [64]
    const float* __restrict__ beta_a,      // [64]
    const float* __restrict__ accum_prev,  // [B][33][64] summed, or null
    float* __restrict__ accum_out,         // [B][33][64] pre-zeroed
    float inv_temp)                        // temperature of the PREV iter
{
    __shared__ float stats_s[ACC_PER_B];   // 8448 B (slot32 = zzb - K)
    __shared__ float red[2][ACC_PER_B];    // 16.9 KB tree-reduce buffers

    const int b = blockIdx.y;
    const int sg = blockIdx.x >> 3;        // site-group 0..1 (32 sites each)
    const int ig = blockIdx.x & 7;         // i-group 0..7 (4 i each)
    const int s0 = sg * 32;
    const int tid = threadIdx.x;
    const int w = tid >> 6;                // wave 0..3 -> i = ig*4+w
    const int o = tid & 63;                // lane = output capsule
    const int i = ig * 4 + w;

    // ---- wave-persistent w row: loaded once ----
    const float4* wp = (const float4*)(wmat + ((size_t)i * 64 + o) * 16);
    float4 w0 = wp[0], w1 = wp[1], w2 = wp[2], w3 = wp[3];

    // ---- stats of previous pass: WAVE 0 ONLY -> stats_s ----
    if (!FIRST && tid < 64) {
        const float* ap = accum_prev + (size_t)b * ACC_PER_B;
        float rps = ap[32 * 64 + o];
        float rinv = 1.0f / rps;
        float logsum = 0.f;
        float mm[16], vv[16];
        #pragma unroll
        for (int p = 0; p < 16; p++) {
            float mv = ap[p * 64 + o] * rinv;
            float va = fmaxf(ap[(16 + p) * 64 + o] * rinv - mv * mv, 0.f);
            mm[p] = mv;
            vv[p] = va;
            logsum += __logf(sqrtf(va) + EPSF);
        }
        float cost = rps * (16.0f * beta_v[o] + logsum);
        float cm = cost;
        #pragma unroll
        for (int s = 32; s > 0; s >>= 1) cm += __shfl_xor(cm, s, 64);
        cm *= (1.0f / 64.0f);
        float dd = cost - cm;
        float cs = dd * dd;
        #pragma unroll
        for (int s = 32; s > 0; s >>= 1) cs += __shfl_xor(cs, s, 64);
        cs = sqrtf(cs * (1.0f / 64.0f));
        float x = inv_temp * (beta_a[o] + (cm - cost) / (cs + EPSF));
        float oa = 1.0f / (1.0f + __expf(-x));
        float zzb = __logf(oa + EPSF) - logsum;
        // softmax shift constant: K = max over the 64 o-lanes of zzb
        float K = zzb;
        #pragma unroll
        for (int s = 32; s > 0; s >>= 1) K = fmaxf(K, __shfl_xor(K, s, 64));
        #pragma unroll
        for (int p = 0; p < 16; p++) stats_s[p * 64 + o] = mm[p];
        #pragma unroll
        for (int p = 0; p < 16; p++) stats_s[(16 + p) * 64 + o] = 0.5f / vv[p];
        stats_s[32 * 64 + o] = zzb - K;
    }
    __syncthreads();   // stats visible

    float m[16], i2v[16], zzbK = 0.f;
    if (!FIRST) {
        #pragma unroll
        for (int p = 0; p < 16; p++) m[p] = stats_s[p * 64 + o];
        #pragma unroll
        for (int p = 0; p < 16; p++) i2v[p] = stats_s[(16 + p) * 64 + o];
        zzbK = stats_s[32 * 64 + o];
    }

    float accR = 0.f, acc1[16], acc2[16];
    #pragma unroll
    for (int p = 0; p < 16; p++) { acc1[p] = 0.f; acc2[p] = 0.f; }

    // wave-uniform base index for scalar pose/act loads
    const int base_n = __builtin_amdgcn_readfirstlane(s0 * 32 + i);
    const float* pose_b = pose + (size_t)b * NN * 16;
    const float* act_b  = act + (size_t)b * NN;

    // ---- inner loop over 32 sites: zero LDS reads; pose/act on SMEM ----
    for (int sl = 0; sl < 32; sl++) {
        const int site = s0 + sl;
        const float c0 = ((site >> 3) + 0.5f) * 0.125f;
        const float c1 = ((site & 7) + 0.5f) * 0.125f;
        const int n = base_n + sl * 32;                 // wave-uniform
        const float4* pr4 = (const float4*)(pose_b + (size_t)n * 16);
        const float av = act_b[n];                      // scalar load

        float v[16];
        #pragma unroll
        for (int a = 0; a < 4; a++) {
            float4 pa = pr4[a];                         // s_load_dwordx4
            v[a * 4 + 0] = pa.x * w0.x + pa.y * w1.x + pa.z * w2.x + pa.w * w3.x;
            v[a * 4 + 1] = pa.x * w0.y + pa.y * w1.y + pa.z * w2.y + pa.w * w3.y;
            v[a * 4 + 2] = pa.x * w0.z + pa.y * w1.z + pa.z * w2.z + pa.w * w3.z;
            v[a * 4 + 3] = pa.x * w0.w + pa.y * w1.w + pa.z * w2.w + pa.w * w3.w;
        }
        v[0] += c0;
        v[1] += c1;

        float rr;
        if (FIRST) {
            rr = 1.0f / 64.0f;
        } else {
            float d = zzbK;
            #pragma unroll
            for (int p = 0; p < 16; p++) {
                float t = v[p] - m[p];
                d -= t * t * i2v[p];
            }
            // shifted softmax: exponent <= 0 by construction (no max pass)
            float e = __expf(d);
            float sum = e;
            #pragma unroll
            for (int s = 32; s > 0; s >>= 1) sum += __shfl_xor(sum, s, 64);
            rr = e / fmaxf(sum, 1e-30f);
        }
        float rp = rr * av;
        accR += rp;
        #pragma unroll
        for (int p = 0; p < 16; p++) {
            acc1[p] += rp * v[p];
            acc2[p] += rp * v[p] * v[p];
        }
    }

    // ---- R1-proven non-atomic 4-wave tree reduce, then wave0 atomics ----
    if (w >= 2) {
        float* r = red[w - 2];
        r[32 * 64 + o] = accR;
        #pragma unroll
        for (int p = 0; p < 16; p++) r[p * 64 + o] = acc1[p];
        #pragma unroll
        for (int p = 0; p < 16; p++) r[(16 + p) * 64 + o] = acc2[p];
    }
    __syncthreads();
    if (w < 2) {
        const float* r = red[w];
        accR += r[32 * 64 + o];
        #pragma unroll
        for (int p = 0; p < 16; p++) acc1[p] += r[p * 64 + o];
        #pragma unroll
        for (int p = 0; p < 16; p++) acc2[p] += r[(16 + p) * 64 + o];
    }
    __syncthreads();
    if (w == 1) {
        float* r = red[0];
        r[32 * 64 + o] = accR;
        #pragma unroll
        for (int p = 0; p < 16; p++) r[p * 64 + o] = acc1[p];
        #pragma unroll
        for (int p = 0; p < 16; p++) r[(16 + p) * 64 + o] = acc2[p];
    }
    __syncthreads();
    if (w == 0) {
        const float* r = red[0];
        accR += r[32 * 64 + o];
        #pragma unroll
        for (int p = 0; p < 16; p++) acc1[p] += r[p * 64 + o];
        #pragma unroll
        for (int p = 0; p < 16; p++) acc2[p] += r[(16 + p) * 64 + o];

        float* ac = accum_out + (size_t)b * ACC_PER_B;
        atomicAdd(ac + 32 * 64 + o, accR);
        #pragma unroll
        for (int p = 0; p < 16; p++) atomicAdd(ac + p * 64 + o, acc1[p]);
        #pragma unroll
        for (int p = 0; p < 16; p++) atomicAdd(ac + (16 + p) * 64 + o, acc2[p]);
    }
}

__global__ __launch_bounds__(64) void stats_final(
    const float* __restrict__ accum,   // [B][33][64] summed
    const float* __restrict__ beta_v,  // [64]
    const float* __restrict__ beta_a,  // [64]
    float* __restrict__ out,
    float inv_temp)
{
    const int b = blockIdx.x;
    const int o = threadIdx.x;  // 64 threads = 1 wave
    const float* ac = accum + (size_t)b * ACC_PER_B;

    float rps = ac[32 * 64 + o];
    float rinv = 1.0f / rps;
    float m[16];
    float logsum = 0.f;
    #pragma unroll
    for (int p = 0; p < 16; p++) {
        float mm = ac[p * 64 + o] * rinv;
        float vv = fmaxf(ac[(16 + p) * 64 + o] * rinv - mm * mm, 0.f);
        m[p] = mm;
        logsum += __logf(sqrtf(vv) + EPSF);
    }
    float cost = rps * (16.0f * beta_v[o] + logsum);

    float cm = cost;
    #pragma unroll
    for (int s = 32; s > 0; s >>= 1) cm += __shfl_xor(cm, s, 64);
    cm *= (1.0f / 64.0f);
    float dd = cost - cm;
    float cs = dd * dd;
    #pragma unroll
    for (int s = 32; s > 0; s >>= 1) cs += __shfl_xor(cs, s, 64);
    cs = sqrtf(cs * (1.0f / 64.0f));

    float x = inv_temp * (beta_a[o] + (cm - cost) / (cs + EPSF));
    float oa = 1.0f / (1.0f + __expf(-x));

    float* op = out + ((size_t)b * 64 + o) * 16;
    #pragma unroll
    for (int p = 0; p < 16; p++) op[p] = m[p];
    out[(size_t)NB * NO * NP + (size_t)b * 64 + o] = oa;
}

extern "C" void kernel_launch(void* const* d_in, const int* in_sizes, int n_in,
                              void* d_out, int out_size, void* d_ws, size_t ws_size,
                              hipStream_t stream) {
    const float* pose   = (const float*)d_in[0];  // (32,8,8,32,4,4)
    const float* act    = (const float*)d_in[1];  // (32,8,8,32)
    const float* wmat   = (const float*)d_in[2];  // (32,64,4,4)
    const float* beta_v = (const float*)d_in[3];  // (1,64)
    const float* beta_a = (const float*)d_in[4];  // (1,64)
    float* out = (float*)d_out;
    float* ws = (float*)d_ws;

    float* a0 = ws;
    float* a1 = ws + (size_t)ACC_TOTAL;
    float* a2 = ws + 2 * (size_t)ACC_TOTAL;

    // zero the three atomic accumulators (ws is poisoned before every call)
    hipMemsetAsync(ws, 0, 3 * (size_t)ACC_TOTAL * sizeof(float), stream);

    dim3 grid(16, NB);   // 512 WGs x 256 thd
    accum_kernel<true ><<<grid, 256, 0, stream>>>(pose, act, wmat, beta_v, beta_a,
                                                  nullptr, a0, 0.0f);
    accum_kernel<false><<<grid, 256, 0, stream>>>(pose, act, wmat, beta_v, beta_a,
                                                  a0, a1, 1.0f);
    accum_kernel<false><<<grid, 256, 0, stream>>>(pose, act, wmat, beta_v, beta_a,
                                                  a1, a2, 2.0f);
    stats_final<<<NB, 64, 0, stream>>>(a2, beta_v, beta_a, out, 3.0f);
}